// Round 7
// baseline (526.917 us; speedup 1.0000x reference)
//
#include <hip/hip_runtime.h>
#include <cstdint>

#define NROW 6144
#define KDIM 128
#define NLAB 200
#define C_COEF (-0.28719499063341177f)   /* -ln(99)/16 ; A_COEF = 2 exactly */
#define UBV 64.0f

typedef _Float16 f16x8 __attribute__((ext_vector_type(8)));
typedef float f32x4 __attribute__((ext_vector_type(4)));
typedef __attribute__((address_space(1))) const void as1c_void;
typedef __attribute__((address_space(3))) void as3_void;

__device__ __forceinline__ float softplus_f(float x){
  return fmaxf(x, 0.f) + __logf(1.f + __expf(-fabsf(x)));
}
__device__ __forceinline__ float waveAllRedF(float v){
#pragma unroll
  for (int o = 32; o; o >>= 1) v += __shfl_down(v, o, 64);
  return __shfl(v, 0, 64);
}
__device__ __forceinline__ int waveAllRedI(int v){
#pragma unroll
  for (int o = 32; o; o >>= 1) v += __shfl_down(v, o, 64);
  return __shfl(v, 0, 64);
}
__device__ __forceinline__ int bucket_of(float v){
  int b = (int)fmaf(v, 2.f, 128.f);
  return b < 0 ? 0 : (b > 255 ? 255 : b);
}
__device__ __forceinline__ unsigned key16_of(_Float16 h){
  unsigned short b = __builtin_bit_cast(unsigned short, h);
  return (b & 0x8000u) ? (unsigned)((unsigned short)~b) : (unsigned)(b | 0x8000u);
}
__device__ __forceinline__ float key16_dec(unsigned k){
  unsigned short b = (k & 0x8000u) ? (unsigned short)(k & 0x7FFFu)
                                   : (unsigned short)(~k & 0xFFFFu);
  return (float)__builtin_bit_cast(_Float16, b);
}
// similar-member value accessor: LDS for t<128 (typical ns~31), global fallback
__device__ __forceinline__ float simget(const float* simv, const _Float16* rowp,
                                        const int* mlist, int t){
  return (t < 128) ? simv[t] : (float)rowp[mlist[t]];
}

// ---------------- labels + per-label histogram + member lists ----------------
__global__ void k_label(const int* __restrict__ y, unsigned char* __restrict__ lab,
                        int* __restrict__ cnt, int* __restrict__ simIdx){
  const int row = blockIdx.x;
  const int t = threadIdx.x;
  if (t < NLAB){
    if (y[(size_t)row * NLAB + t] != 0){
      lab[row] = (unsigned char)t;
      int p = atomicAdd(&cnt[t], 1);
      if (p < 512) simIdx[t * 512 + p] = row;
    }
  }
}

// ---------------- tanh -> swizzled f16, + quantization-loss partial ----------------
__global__ __launch_bounds__(256) void k_tanh(const float* __restrict__ u,
    _Float16* __restrict__ uhswz, float* __restrict__ accf){
  const int tid = threadIdx.x;
  const int gid = blockIdx.x * 256 + tid;
  const int row = gid >> 4;
  const int h = gid & 15;
  const int g = h ^ (row & 7);
  const float* sp = u + (size_t)row * KDIM + g * 8;
  float q = 0.f;
  f16x8 o;
#pragma unroll
  for (int t = 0; t < 8; t++){
    float x = sp[t];
    float e2 = __expf(2.f * x);
    float th = 1.f - 2.f * __builtin_amdgcn_rcpf(e2 + 1.f);
    float sg = (th > 0.f) ? 1.f : ((th < 0.f) ? -1.f : 0.f);
    float d = th - sg;
    q += d * d;
    o[t] = (_Float16)th;
  }
  *(f16x8*)(uhswz + (size_t)row * KDIM + h * 8) = o;
  q = waveAllRedF(q);
  __shared__ float qb[4];
  if ((tid & 63) == 0) qb[tid >> 6] = q;
  __syncthreads();
  if (tid == 0) atomicAdd(&accf[0], qb[0] + qb[1] + qb[2] + qb[3]);
}

// ---------------- inner = uh @ uh^T -> f16 out via LDS-transpose epilogue ----------------
__global__ __launch_bounds__(256) void k_mm(const _Float16* __restrict__ A,
    _Float16* __restrict__ out, int row0){
  __shared__ __align__(16) _Float16 SH[2 * 128 * KDIM];
  _Float16* As = SH;
  _Float16* Bs = SH + 128 * KDIM;
  const int tid = threadIdx.x;
  const int wav = tid >> 6, lane = tid & 63;
  const int bj = blockIdx.x, bi = blockIdx.y;

  const char* Ag = (const char*)(A + (size_t)(row0 + bi * 128) * KDIM);
  const char* Bg = (const char*)(A + (size_t)(bj * 128) * KDIM);
  char* Asb = (char*)As;
  char* Bsb = (char*)Bs;
#pragma unroll
  for (int t = 0; t < 8; t++){
    const int ub = wav * 8192 + t * 1024;
    __builtin_amdgcn_global_load_lds((as1c_void*)(Ag + ub + lane * 16),
                                     (as3_void*)(Asb + ub), 16, 0, 0);
    __builtin_amdgcn_global_load_lds((as1c_void*)(Bg + ub + lane * 16),
                                     (as3_void*)(Bsb + ub), 16, 0, 0);
  }
  __syncthreads();

  const int quad = lane >> 4, l16 = lane & 15;
  const int wm = (wav >> 1) * 64, wn = (wav & 1) * 64;
  f32x4 acc[4][4];
#pragma unroll
  for (int im = 0; im < 4; im++)
#pragma unroll
    for (int in = 0; in < 4; in++)
      acc[im][in] = (f32x4){0.f, 0.f, 0.f, 0.f};

#pragma unroll
  for (int kb = 0; kb < 4; kb++){
    f16x8 af[4], bf[4];
#pragma unroll
    for (int i = 0; i < 4; i++){
      const int m = wm + i * 16 + l16;
      const int gidx = kb * 4 + quad;
      af[i] = *(const f16x8*)(Asb + m * 256 + ((gidx ^ (m & 7)) << 4));
      const int n = wn + i * 16 + l16;
      bf[i] = *(const f16x8*)(Bsb + n * 256 + ((gidx ^ (n & 7)) << 4));
    }
#pragma unroll
    for (int im = 0; im < 4; im++)
#pragma unroll
      for (int in = 0; in < 4; in++)
        acc[im][in] = __builtin_amdgcn_mfma_f32_16x16x32_f16(af[im], bf[in], acc[im][in], 0, 0, 0);
  }
  __syncthreads();

  _Float16* Cs = SH;
#pragma unroll
  for (int im = 0; im < 4; im++)
#pragma unroll
    for (int in = 0; in < 4; in++)
#pragma unroll
      for (int r = 0; r < 4; r++){
        const int rl = wm + im * 16 + quad * 4 + r;
        const int cl = wn + in * 16 + l16;
        Cs[rl * 132 + cl] = (_Float16)acc[im][in][r];
      }
  __syncthreads();

  _Float16* obase = out + (size_t)(bi * 128) * NROW + (size_t)bj * 128;
  const int s = tid & 15;
#pragma unroll
  for (int i = 0; i < 8; i++){
    const int r = (tid >> 4) + i * 16;
    f16x8 vv = *(const f16x8*)(Cs + r * 132 + s * 8);
    *(f16x8*)(obase + (size_t)r * NROW + s * 8) = vv;
  }
}

// ---------------- per-row stats + loss: one WAVE per row, row streamed from L2 ----------------
// Zero __syncthreads. Per-wave private LDS (hist 1KB + cand 3KB + simv 0.5KB).
// All sweeps are mask-free over all 6144 elems; the ~31 same-class elements are
// corrected via the member list (integer-exact for ranks/counts). 3 row streams.
__global__ __launch_bounds__(256, 6) void k_stats(const _Float16* __restrict__ buf,
    const unsigned char* __restrict__ lab, const int* __restrict__ cnt,
    const int* __restrict__ simIdx, float* __restrict__ accf,
    int* __restrict__ acci, int row0){
  __shared__ int histS[4 * 256];        // 4096 B
  __shared__ float candS[4 * 768];      // 12288 B
  __shared__ float simvS[4 * 128];      // 2048 B
  __shared__ int ctlS[4 * 8];           // 128 B

  const int lane = threadIdx.x & 63;
  const int wav = threadIdx.x >> 6;
  int* hist = histS + wav * 256;
  float* cand = candS + wav * 768;
  float* simv = simvS + wav * 128;
  int* ctl = ctlS + wav * 8;

  const int lrow = blockIdx.x * 4 + wav;
  const int row = row0 + lrow;
  const int myl = lab[row];
  const int n_sim = cnt[myl];
  const int n_dis = NROW - n_sim;
  if (n_dis == 0 || n_sim == 0) return;           // per-wave exit, no barriers anywhere
  const int k1 = n_dis - (n_dis * 9) / 10;
  const int k2 = n_sim - (n_sim * 9) / 10;
  const int ns = (n_sim < 512) ? n_sim : 512;

#pragma unroll
  for (int i = 0; i < 4; i++) hist[lane + 64 * i] = 0;
  if (lane == 0) ctl[0] = 0;                      // wave-ordered LDS: no fence needed

  const f16x8* src = (const f16x8*)(buf + (size_t)lrow * NROW);
  const _Float16* rowp = buf + (size_t)lrow * NROW;
  const int* mlist = simIdx + myl * 512;

  // ---- sweep 1: mask-free histogram + total sum ----
  float sumAll = 0.f;
#pragma unroll 2
  for (int j = 0; j < 12; j++){
    f16x8 h8 = src[j * 64 + lane];
#pragma unroll
    for (int e = 0; e < 8; e++){
      float v = (float)h8[e];
      sumAll += v;
      atomicAdd(&hist[bucket_of(v)], 1);
    }
  }
  // sim gather + exact histogram correction
  float sumS = 0.f;
  for (int t = lane; t < ns; t += 64){
    int idx = mlist[t];
    float v = (float)rowp[idx];
    if (t < 128) simv[t] = v;
    sumS += v;
    atomicAdd(&hist[bucket_of(v)], -1);
  }
  sumAll = waveAllRedF(sumAll);
  sumS = waveAllRedF(sumS);
  const float sumDS = sumAll - sumS;

  // ---- pivot bucket select (wave suffix scan, ballot broadcast) ----
  int c4[4], part = 0;
#pragma unroll
  for (int d = 0; d < 4; d++){ c4[d] = hist[4 * lane + d]; part += c4[d]; }
  int suf = part;
#pragma unroll
  for (int o = 1; o < 64; o <<= 1){ int x = __shfl_down(suf, o, 64); if (lane + o < 64) suf += x; }
  int cum = suf - part;
  int kr0 = 0, cntB = 0, pb = 0; bool found = false;
#pragma unroll
  for (int d = 3; d >= 0; --d){
    if (!found && k1 > cum && k1 <= cum + c4[d]){
      kr0 = k1 - cum; cntB = c4[d]; pb = 4 * lane + d; found = true;
    }
    cum += c4[d];
  }
  {
    unsigned long long bm = __ballot(found);
    int sl = __ffsll(bm) - 1;
    kr0 = __shfl(kr0, sl, 64); cntB = __shfl(cntB, sl, 64); pb = __shfl(pb, sl, 64);
  }
  const float thrLo = (pb == 0) ? -1e30f : (float)(pb - 128) * 0.5f;
  const float thrHi = (pb == 255) ? 1e30f : (float)(pb - 127) * 0.5f;

  // ---- sweep 2: mask-free above-bucket sum + in-bucket collect (sims included) ----
  float sAb = 0.f;
#pragma unroll 2
  for (int j = 0; j < 12; j++){
    f16x8 h8 = src[j * 64 + lane];
#pragma unroll
    for (int e = 0; e < 8; e++){
      float v = (float)h8[e];
      if (v >= thrHi) sAb += v;
      else if (v >= thrLo){
        int p = atomicAdd(&ctl[0], 1);
        if (p < 768) cand[p] = v;
      }
    }
  }
  float sAbS = 0.f;
  for (int t = lane; t < ns; t += 64){
    float vs = simget(simv, rowp, mlist, t);
    if (vs >= thrHi) sAbS += vs;
  }
  sAb = waveAllRedF(sAb) - waveAllRedF(sAbS);
  const int ncg = ctl[0];

  float dSum;
  if (ncg <= 768){
    // rank-count with register-cached candidates + sim corrections (integer-exact)
    float vt[12]; int gt[12], eq[12];
    const int nk = (ncg + 63) >> 6;
#pragma unroll
    for (int k = 0; k < 12; k++){
      int t = k * 64 + lane;
      vt[k] = (k < nk && t < ncg) ? cand[t] : 0.f;
      gt[k] = 0; eq[k] = 0;
    }
    for (int j2 = 0; j2 < ncg; j2++){
      float vj = cand[j2];
#pragma unroll
      for (int k = 0; k < 12; k++){
        if (k < nk){ gt[k] += (vj > vt[k]); eq[k] += (vj == vt[k]); }
      }
    }
    for (int t2 = 0; t2 < ns; t2++){
      float vs = simget(simv, rowp, mlist, t2);
      if (vs >= thrLo && vs < thrHi){
#pragma unroll
        for (int k = 0; k < 12; k++){
          if (k < nk){ gt[k] -= (vs > vt[k]); eq[k] -= (vs == vt[k]); }
        }
      }
    }
    float pivW = 0.f; int gtW = 0; bool fw = false;
#pragma unroll
    for (int k = 0; k < 12; k++){
      int t = k * 64 + lane;
      if (k < nk && t < ncg && !fw && gt[k] < kr0 && kr0 <= gt[k] + eq[k]){
        pivW = vt[k]; gtW = gt[k]; fw = true;
      }
    }
    unsigned long long bm2 = __ballot(fw);
    int s2 = __ffsll(bm2) - 1;
    const float piv = __shfl(pivW, s2, 64);
    const int gtS = __shfl(gtW, s2, 64);
    // in-bucket above-pivot sum from register candidates, minus sim part
    float sg = 0.f;
#pragma unroll
    for (int k = 0; k < 12; k++){
      int t = k * 64 + lane;
      if (k < nk && t < ncg && vt[k] > piv) sg += vt[k];
    }
    float sgS = 0.f;
    for (int t = lane; t < ns; t += 64){
      float vs = simget(simv, rowp, mlist, t);
      if (vs >= thrLo && vs < thrHi && vs > piv) sgS += vs;
    }
    sg = waveAllRedF(sg) - waveAllRedF(sgS);
    dSum = sAb + sg + (float)(kr0 - gtS) * piv;
  } else {
    // guard (never expected): exact f16-key bisection, mask-free + sim subtract
    unsigned lo = 0u, hi = 65535u;
    while (lo < hi){
      unsigned mid = (lo + hi) >> 1;
      int c = 0;
      for (int j = 0; j < 12; j++){
        f16x8 h8 = src[j * 64 + lane];
#pragma unroll
        for (int e = 0; e < 8; e++){
          float v = (float)h8[e];
          if (v >= thrLo && v < thrHi && key16_of(h8[e]) > mid) c++;
        }
      }
      for (int t = lane; t < ns; t += 64){
        float vs = simget(simv, rowp, mlist, t);
        if (vs >= thrLo && vs < thrHi && key16_of((_Float16)vs) > mid) c--;
      }
      c = waveAllRedI(c);
      if (c >= kr0) lo = mid + 1; else hi = mid;
    }
    const float piv = key16_dec(lo);
    float sg = 0.f; int cg = 0;
    for (int j = 0; j < 12; j++){
      f16x8 h8 = src[j * 64 + lane];
#pragma unroll
      for (int e = 0; e < 8; e++){
        float v = (float)h8[e];
        if (v >= thrLo && v < thrHi && key16_of(h8[e]) > lo){ sg += v; cg++; }
      }
    }
    for (int t = lane; t < ns; t += 64){
      float vs = simget(simv, rowp, mlist, t);
      if (vs >= thrLo && vs < thrHi && key16_of((_Float16)vs) > lo){ sg -= vs; cg--; }
    }
    sg = waveAllRedF(sg); cg = waveAllRedI(cg);
    dSum = sAb + sg + (float)(kr0 - cg) * piv;
  }

  // ---- sMin: k2-th smallest similar (rank-count on member list) ----
  float piv2 = 0.f; int ltS = 0;
  {
    float pw = 0.f; int lw = 0; bool fw = false;
    for (int t = lane; t < ns; t += 64){
      float vt2 = simget(simv, rowp, mlist, t);
      int lt = 0, eq = 0;
      for (int j2 = 0; j2 < ns; j2++){
        float vj = simget(simv, rowp, mlist, j2);
        lt += (vj < vt2); eq += (vj == vt2);
      }
      if (!fw && lt < k2 && k2 <= lt + eq){ pw = vt2; lw = lt; fw = true; }
    }
    unsigned long long bm3 = __ballot(fw);
    int s3 = __ffsll(bm3) - 1;
    piv2 = __shfl(pw, s3, 64); ltS = __shfl(lw, s3, 64);
  }
  float slt = 0.f;
  for (int t = lane; t < ns; t += 64){
    float vs = simget(simv, rowp, mlist, t);
    if (vs < piv2) slt += vs;
  }
  slt = waveAllRedF(slt);
  const float sSum = slt + (float)(k2 - ltS) * piv2;

  // ---- BP/BPd ----
  const float meanS = fminf(fmaxf(sumS / fmaxf((float)n_sim, 1.f), 0.f), UBV);
  const float meanDS = fminf(fmaxf(sumDS / fmaxf((float)n_dis, 1.f), 0.f), UBV);
  const float dMax = fminf(fmaxf(dSum / fmaxf((float)k1, 1.f), 0.f), UBV);
  const float sMin = fminf(fmaxf(sSum / fmaxf((float)k2, 1.f), 0.f), UBV);
  const float BP = meanS - (UBV - meanS) / UBV * fabsf(meanS - dMax);
  const float BPd = meanDS + meanDS / UBV * fabsf(meanDS - sMin);

  // ---- sweep 3: mask-free dissim loss over ALL elems, subtract sim terms ----
  float anA = 0.f, cnA = 0.f;
#pragma unroll 2
  for (int j = 0; j < 12; j++){
    f16x8 h8 = src[j * 64 + lane];
#pragma unroll
    for (int e = 0; e < 8; e++){
      float v = (float)h8[e];
      float dcd = v - BPd;
      float f = ((v < BPd) ? C_COEF : 2.f * C_COEF) * dcd;
      float sp = softplus_f(-f);
      bool use = (v != BPd);
      anA += use ? sp : 0.f;
      cnA += use ? 1.f : 0.f;
    }
  }
  float anS = 0.f, cnS = 0.f, ap = 0.f, cp = 0.f;
  for (int t = lane; t < ns; t += 64){
    float v = simget(simv, rowp, mlist, t);
    float dcd = v - BPd;
    float f = ((v < BPd) ? C_COEF : 2.f * C_COEF) * dcd;
    if (v != BPd){ anS += softplus_f(-f); cnS += 1.f; }   // bitwise-identical terms
    if (v != BP){
      float dc = v - BP;
      float f2 = ((v > BP) ? C_COEF : 2.f * C_COEF) * dc;
      ap += softplus_f(f2); cp += 1.f;
    }
  }
  const float an = waveAllRedF(anA) - waveAllRedF(anS);
  const float cn = waveAllRedF(cnA) - waveAllRedF(cnS);
  const float apT = waveAllRedF(ap);
  const float cpT = waveAllRedF(cp);
  if (lane == 0){
    atomicAdd(&accf[1], apT / fmaxf(cpT, 1.f));
    atomicAdd(&accf[2], an / fmaxf(cn, 1.f));
    atomicAdd(&acci[3], 1);
  }
}

__global__ void k_final(const float* __restrict__ accf, const int* __restrict__ acci,
                        float* __restrict__ out){
  if (threadIdx.x == 0 && blockIdx.x == 0){
    int c = acci[3];
    float posL = 0.f, navL = 0.f;
    if (c > 0){ posL = accf[1] / (float)c; navL = accf[2] / (float)c; }
    out[0] = posL + navL + 0.1f * (accf[0] / (float)(NROW * KDIM));
  }
}

extern "C" void kernel_launch(void* const* d_in, const int* in_sizes, int n_in,
                              void* d_out, int out_size, void* d_ws, size_t ws_size,
                              hipStream_t stream){
  const float* u = (const float*)d_in[0];
  const int* y = (const int*)d_in[1];
  char* ws = (char*)d_ws;
  float* accf = (float*)ws;                        // [0]=qSum [1]=posSum [2]=negSum
  int* acci = (int*)ws;                            // [3]=validCount
  int* cnt = (int*)(ws + 64);                      // 256 ints
  unsigned char* lab = (unsigned char*)(ws + 4096);        // 6144 B
  int* simIdx = (int*)(ws + 12288);                // 200*512 ints = 409600 B
  _Float16* uhswz = (_Float16*)(ws + 425984);      // 1572864 B
  const size_t ibufOff = 425984 + (size_t)NROW * KDIM * 2; // 1998848, 16B aligned
  _Float16* ibuf = (_Float16*)(ws + ibufOff);

  hipMemsetAsync(d_ws, 0, 4096, stream);           // accumulators + class counts
  k_label<<<NROW, 256, 0, stream>>>(y, lab, cnt, simIdx);
  k_tanh<<<(NROW * 16) / 256, 256, 0, stream>>>(u, uhswz, accf);

  size_t avail = (ws_size > ibufOff) ? ws_size - ibufOff : 0;
  long maxRows = (long)(avail / ((size_t)NROW * 2));
  maxRows = (maxRows / 128) * 128;
  if (maxRows > NROW) maxRows = NROW;
  if (maxRows < 128) maxRows = 128;

  for (int r0 = 0; r0 < NROW; r0 += (int)maxRows){
    int rows = NROW - r0;
    if (rows > maxRows) rows = (int)maxRows;
    k_mm<<<dim3(48, rows / 128), 256, 0, stream>>>(uhswz, ibuf, r0);
    k_stats<<<rows / 4, 256, 0, stream>>>(ibuf, lab, cnt, simIdx, accf, acci, r0);
  }
  k_final<<<1, 64, 0, stream>>>(accf, acci, (float*)d_out);
}

// Round 8
// 388.216 us; speedup vs baseline: 1.3573x; 1.3573x over previous
//
#include <hip/hip_runtime.h>
#include <cstdint>

#define NROW 6144
#define KDIM 128
#define NLAB 200
#define C_COEF (-0.28719499063341177f)   /* -ln(99)/16 ; A_COEF = 2 exactly */
#define UBV 64.0f

typedef _Float16 f16x8 __attribute__((ext_vector_type(8)));
typedef float f32x4 __attribute__((ext_vector_type(4)));
typedef __attribute__((address_space(1))) const void as1c_void;
typedef __attribute__((address_space(3))) void as3_void;

__device__ __forceinline__ float softplus_f(float x){
  return fmaxf(x, 0.f) + __logf(1.f + __expf(-fabsf(x)));
}
__device__ __forceinline__ float waveAllRedF(float v){
#pragma unroll
  for (int o = 32; o; o >>= 1) v += __shfl_down(v, o, 64);
  return __shfl(v, 0, 64);
}
__device__ __forceinline__ int waveAllRedI(int v){
#pragma unroll
  for (int o = 32; o; o >>= 1) v += __shfl_down(v, o, 64);
  return __shfl(v, 0, 64);
}
__device__ __forceinline__ int bucket_of(float v){
  int b = (int)fmaf(v, 2.f, 128.f);
  return b < 0 ? 0 : (b > 255 ? 255 : b);
}
__device__ __forceinline__ unsigned key16_of(_Float16 h){
  unsigned short b = __builtin_bit_cast(unsigned short, h);
  return (b & 0x8000u) ? (unsigned)((unsigned short)~b) : (unsigned)(b | 0x8000u);
}
__device__ __forceinline__ float key16_dec(unsigned k){
  unsigned short b = (k & 0x8000u) ? (unsigned short)(k & 0x7FFFu)
                                   : (unsigned short)(~k & 0xFFFFu);
  return (float)__builtin_bit_cast(_Float16, b);
}
__device__ __forceinline__ float simget(const float* simv, const _Float16* rowp,
                                        const int* mlist, int t){
  return (t < 128) ? simv[t] : (float)rowp[mlist[t]];
}

// ---------------- labels + per-label histogram + member lists ----------------
__global__ void k_label(const int* __restrict__ y, unsigned char* __restrict__ lab,
                        int* __restrict__ cnt, int* __restrict__ simIdx){
  const int row = blockIdx.x;
  const int t = threadIdx.x;
  if (t < NLAB){
    if (y[(size_t)row * NLAB + t] != 0){
      lab[row] = (unsigned char)t;
      int p = atomicAdd(&cnt[t], 1);
      if (p < 512) simIdx[t * 512 + p] = row;
    }
  }
}

// ---------------- tanh -> swizzled f16, + quantization-loss partial ----------------
__global__ __launch_bounds__(256) void k_tanh(const float* __restrict__ u,
    _Float16* __restrict__ uhswz, float* __restrict__ accf){
  const int tid = threadIdx.x;
  const int gid = blockIdx.x * 256 + tid;
  const int row = gid >> 4;
  const int h = gid & 15;
  const int g = h ^ (row & 7);
  const float* sp = u + (size_t)row * KDIM + g * 8;
  float q = 0.f;
  f16x8 o;
#pragma unroll
  for (int t = 0; t < 8; t++){
    float x = sp[t];
    float e2 = __expf(2.f * x);
    float th = 1.f - 2.f * __builtin_amdgcn_rcpf(e2 + 1.f);
    float sg = (th > 0.f) ? 1.f : ((th < 0.f) ? -1.f : 0.f);
    float d = th - sg;
    q += d * d;
    o[t] = (_Float16)th;
  }
  *(f16x8*)(uhswz + (size_t)row * KDIM + h * 8) = o;
  q = waveAllRedF(q);
  __shared__ float qb[4];
  if ((tid & 63) == 0) qb[tid >> 6] = q;
  __syncthreads();
  if (tid == 0) atomicAdd(&accf[0], qb[0] + qb[1] + qb[2] + qb[3]);
}

// ---------------- inner = uh @ uh^T -> f16 out via LDS-transpose epilogue ----------------
__global__ __launch_bounds__(256) void k_mm(const _Float16* __restrict__ A,
    _Float16* __restrict__ out, int row0){
  __shared__ __align__(16) _Float16 SH[2 * 128 * KDIM];
  _Float16* As = SH;
  _Float16* Bs = SH + 128 * KDIM;
  const int tid = threadIdx.x;
  const int wav = tid >> 6, lane = tid & 63;
  const int bj = blockIdx.x, bi = blockIdx.y;

  const char* Ag = (const char*)(A + (size_t)(row0 + bi * 128) * KDIM);
  const char* Bg = (const char*)(A + (size_t)(bj * 128) * KDIM);
  char* Asb = (char*)As;
  char* Bsb = (char*)Bs;
#pragma unroll
  for (int t = 0; t < 8; t++){
    const int ub = wav * 8192 + t * 1024;
    __builtin_amdgcn_global_load_lds((as1c_void*)(Ag + ub + lane * 16),
                                     (as3_void*)(Asb + ub), 16, 0, 0);
    __builtin_amdgcn_global_load_lds((as1c_void*)(Bg + ub + lane * 16),
                                     (as3_void*)(Bsb + ub), 16, 0, 0);
  }
  __syncthreads();

  const int quad = lane >> 4, l16 = lane & 15;
  const int wm = (wav >> 1) * 64, wn = (wav & 1) * 64;
  f32x4 acc[4][4];
#pragma unroll
  for (int im = 0; im < 4; im++)
#pragma unroll
    for (int in = 0; in < 4; in++)
      acc[im][in] = (f32x4){0.f, 0.f, 0.f, 0.f};

#pragma unroll
  for (int kb = 0; kb < 4; kb++){
    f16x8 af[4], bf[4];
#pragma unroll
    for (int i = 0; i < 4; i++){
      const int m = wm + i * 16 + l16;
      const int gidx = kb * 4 + quad;
      af[i] = *(const f16x8*)(Asb + m * 256 + ((gidx ^ (m & 7)) << 4));
      const int n = wn + i * 16 + l16;
      bf[i] = *(const f16x8*)(Bsb + n * 256 + ((gidx ^ (n & 7)) << 4));
    }
#pragma unroll
    for (int im = 0; im < 4; im++)
#pragma unroll
      for (int in = 0; in < 4; in++)
        acc[im][in] = __builtin_amdgcn_mfma_f32_16x16x32_f16(af[im], bf[in], acc[im][in], 0, 0, 0);
  }
  __syncthreads();

  _Float16* Cs = SH;
#pragma unroll
  for (int im = 0; im < 4; im++)
#pragma unroll
    for (int in = 0; in < 4; in++)
#pragma unroll
      for (int r = 0; r < 4; r++){
        const int rl = wm + im * 16 + quad * 4 + r;
        const int cl = wn + in * 16 + l16;
        Cs[rl * 132 + cl] = (_Float16)acc[im][in][r];
      }
  __syncthreads();

  _Float16* obase = out + (size_t)(bi * 128) * NROW + (size_t)bj * 128;
  const int s = tid & 15;
#pragma unroll
  for (int i = 0; i < 8; i++){
    const int r = (tid >> 4) + i * 16;
    f16x8 vv = *(const f16x8*)(Cs + r * 132 + s * 8);
    *(f16x8*)(obase + (size_t)r * NROW + s * 8) = vv;
  }
}

// -------- per-row stats + loss: wave-per-row, row in PER-WAVE PRIVATE LDS --------
// Zero __syncthreads. 4 waves/block, per-wave LDS = row 12KB + hist 1KB +
// cand 2KB + simv 0.5KB = 15.9KB (block 63.6KB -> 2 blocks/CU, 8 indep waves).
// Mask-free sweeps over all 6144 elems; ~31 same-class elems corrected exactly
// via member list (integer-exact ranks/counts; loss terms cancel bitwise).
__global__ __launch_bounds__(256) void k_stats(const _Float16* __restrict__ buf,
    const unsigned char* __restrict__ lab, const int* __restrict__ cnt,
    const int* __restrict__ simIdx, float* __restrict__ accf,
    int* __restrict__ acci, int row0){
  __shared__ __align__(16) _Float16 rowS[4][NROW];  // 49152 B
  __shared__ int histS[4][256];                     // 4096 B
  __shared__ float candS[4][512];                   // 8192 B
  __shared__ float simvS[4][128];                   // 2048 B
  __shared__ int ctlS[4][8];                        // 128 B

  const int lane = threadIdx.x & 63;
  const int wav = threadIdx.x >> 6;
  _Float16* rowL = rowS[wav];
  int* hist = histS[wav];
  float* cand = candS[wav];
  float* simv = simvS[wav];
  int* ctl = ctlS[wav];

  const int lrow = blockIdx.x * 4 + wav;
  const int row = row0 + lrow;
  const int myl = lab[row];
  const int n_sim = cnt[myl];
  const int n_dis = NROW - n_sim;
  if (n_dis == 0 || n_sim == 0) return;            // per-wave exit, no barriers
  const int k1 = n_dis - (n_dis * 9) / 10;
  const int k2 = n_sim - (n_sim * 9) / 10;
  const int ns = (n_sim < 512) ? n_sim : 512;

#pragma unroll
  for (int i = 0; i < 4; i++) hist[lane + 64 * i] = 0;
  if (lane == 0) ctl[0] = 0;

  const f16x8* src = (const f16x8*)(buf + (size_t)lrow * NROW);
  const _Float16* rowp = buf + (size_t)lrow * NROW;
  const int* mlist = simIdx + myl * 512;

  // ---- sweep 1 (fused with row load): global->reg->LDS, hist + total sum ----
  float sumAll = 0.f;
#pragma unroll 2
  for (int j = 0; j < 12; j++){
    f16x8 h8 = src[j * 64 + lane];
    ((f16x8*)rowL)[j * 64 + lane] = h8;
#pragma unroll
    for (int e = 0; e < 8; e++){
      float v = (float)h8[e];
      sumAll += v;
      atomicAdd(&hist[bucket_of(v)], 1);
    }
  }
  // sim gather + exact histogram correction
  float sumS = 0.f;
  for (int t = lane; t < ns; t += 64){
    int idx = mlist[t];
    float v = (float)rowp[idx];
    if (t < 128) simv[t] = v;
    sumS += v;
    atomicAdd(&hist[bucket_of(v)], -1);
  }
  sumAll = waveAllRedF(sumAll);
  sumS = waveAllRedF(sumS);
  const float sumDS = sumAll - sumS;
  __threadfence_block();                           // drain wave's DS ops (no barrier)

  // ---- pivot bucket select (wave suffix scan + ballot broadcast) ----
  int c4[4], part = 0;
#pragma unroll
  for (int d = 0; d < 4; d++){ c4[d] = hist[4 * lane + d]; part += c4[d]; }
  int suf = part;
#pragma unroll
  for (int o = 1; o < 64; o <<= 1){ int x = __shfl_down(suf, o, 64); if (lane + o < 64) suf += x; }
  int cum = suf - part;
  int kr0 = 0, pb = 0; bool found = false;
#pragma unroll
  for (int d = 3; d >= 0; --d){
    if (!found && k1 > cum && k1 <= cum + c4[d]){
      kr0 = k1 - cum; pb = 4 * lane + d; found = true;
    }
    cum += c4[d];
  }
  {
    unsigned long long bm = __ballot(found);
    int sl = __ffsll(bm) - 1;
    kr0 = __shfl(kr0, sl, 64); pb = __shfl(pb, sl, 64);
  }
  const float thrLo = (pb == 0) ? -1e30f : (float)(pb - 128) * 0.5f;
  const float thrHi = (pb == 255) ? 1e30f : (float)(pb - 127) * 0.5f;

  // ---- sweep 2 (LDS row): above-bucket sum + in-bucket collect (sims incl.) ----
  float sAb = 0.f;
#pragma unroll 2
  for (int j = 0; j < 12; j++){
    f16x8 h8 = ((const f16x8*)rowL)[j * 64 + lane];
#pragma unroll
    for (int e = 0; e < 8; e++){
      float v = (float)h8[e];
      if (v >= thrHi) sAb += v;
      else if (v >= thrLo){
        int p = atomicAdd(&ctl[0], 1);
        if (p < 512) cand[p] = v;
      }
    }
  }
  float sAbS = 0.f;
  for (int t = lane; t < ns; t += 64){
    float vs = simget(simv, rowp, mlist, t);
    if (vs >= thrHi) sAbS += vs;
  }
  sAb = waveAllRedF(sAb) - waveAllRedF(sAbS);
  __threadfence_block();
  const int ncg = ctl[0];

  float dSum;
  if (ncg <= 512){
    // exact rank-count on cand (LDS broadcast), sim corrections integer-exact
    float pivW = 0.f; int gtW = 0; bool fw = false;
    for (int t = lane; t < ncg; t += 64){
      float vt = cand[t];
      int gt = 0, eq = 0;
      for (int j2 = 0; j2 < ncg; j2++){
        float vj = cand[j2];
        gt += (vj > vt); eq += (vj == vt);
      }
      for (int t2 = 0; t2 < ns; t2++){
        float vs = simget(simv, rowp, mlist, t2);
        if (vs >= thrLo && vs < thrHi){ gt -= (vs > vt); eq -= (vs == vt); }
      }
      if (!fw && gt < kr0 && kr0 <= gt + eq){ pivW = vt; gtW = gt; fw = true; }
    }
    unsigned long long bm2 = __ballot(fw);
    int s2 = __ffsll(bm2) - 1;
    const float piv = __shfl(pivW, s2, 64);
    const int gtS = __shfl(gtW, s2, 64);
    float sg = 0.f;
    for (int t = lane; t < ncg; t += 64){
      float v = cand[t];
      if (v > piv) sg += v;
    }
    float sgS = 0.f;
    for (int t = lane; t < ns; t += 64){
      float vs = simget(simv, rowp, mlist, t);
      if (vs >= thrLo && vs < thrHi && vs > piv) sgS += vs;
    }
    sg = waveAllRedF(sg) - waveAllRedF(sgS);
    dSum = sAb + sg + (float)(kr0 - gtS) * piv;
  } else {
    // guard (never expected): exact f16-key bisection on LDS row, sim-subtract
    unsigned lo = 0u, hi = 65535u;
    while (lo < hi){
      unsigned mid = (lo + hi) >> 1;
      int c = 0;
      for (int j = 0; j < 12; j++){
        f16x8 h8 = ((const f16x8*)rowL)[j * 64 + lane];
#pragma unroll
        for (int e = 0; e < 8; e++){
          float v = (float)h8[e];
          if (v >= thrLo && v < thrHi && key16_of(h8[e]) > mid) c++;
        }
      }
      for (int t = lane; t < ns; t += 64){
        float vs = simget(simv, rowp, mlist, t);
        if (vs >= thrLo && vs < thrHi && key16_of((_Float16)vs) > mid) c--;
      }
      c = waveAllRedI(c);
      if (c >= kr0) lo = mid + 1; else hi = mid;
    }
    const float piv = key16_dec(lo);
    float sg = 0.f; int cg = 0;
    for (int j = 0; j < 12; j++){
      f16x8 h8 = ((const f16x8*)rowL)[j * 64 + lane];
#pragma unroll
      for (int e = 0; e < 8; e++){
        float v = (float)h8[e];
        if (v >= thrLo && v < thrHi && key16_of(h8[e]) > lo){ sg += v; cg++; }
      }
    }
    for (int t = lane; t < ns; t += 64){
      float vs = simget(simv, rowp, mlist, t);
      if (vs >= thrLo && vs < thrHi && key16_of((_Float16)vs) > lo){ sg -= vs; cg--; }
    }
    sg = waveAllRedF(sg); cg = waveAllRedI(cg);
    dSum = sAb + sg + (float)(kr0 - cg) * piv;
  }

  // ---- sMin: k2-th smallest similar (rank-count on member list) ----
  float piv2 = 0.f; int ltS = 0;
  {
    float pw = 0.f; int lw = 0; bool fw = false;
    for (int t = lane; t < ns; t += 64){
      float vt2 = simget(simv, rowp, mlist, t);
      int lt = 0, eq = 0;
      for (int j2 = 0; j2 < ns; j2++){
        float vj = simget(simv, rowp, mlist, j2);
        lt += (vj < vt2); eq += (vj == vt2);
      }
      if (!fw && lt < k2 && k2 <= lt + eq){ pw = vt2; lw = lt; fw = true; }
    }
    unsigned long long bm3 = __ballot(fw);
    int s3 = __ffsll(bm3) - 1;
    piv2 = __shfl(pw, s3, 64); ltS = __shfl(lw, s3, 64);
  }
  float slt = 0.f;
  for (int t = lane; t < ns; t += 64){
    float vs = simget(simv, rowp, mlist, t);
    if (vs < piv2) slt += vs;
  }
  slt = waveAllRedF(slt);
  const float sSum = slt + (float)(k2 - ltS) * piv2;

  // ---- BP/BPd ----
  const float meanS = fminf(fmaxf(sumS / fmaxf((float)n_sim, 1.f), 0.f), UBV);
  const float meanDS = fminf(fmaxf(sumDS / fmaxf((float)n_dis, 1.f), 0.f), UBV);
  const float dMax = fminf(fmaxf(dSum / fmaxf((float)k1, 1.f), 0.f), UBV);
  const float sMin = fminf(fmaxf(sSum / fmaxf((float)k2, 1.f), 0.f), UBV);
  const float BP = meanS - (UBV - meanS) / UBV * fabsf(meanS - dMax);
  const float BPd = meanDS + meanDS / UBV * fabsf(meanDS - sMin);

  // ---- sweep 3 (LDS row): mask-free dissim loss, subtract sim terms ----
  float anA = 0.f, cnA = 0.f;
#pragma unroll 2
  for (int j = 0; j < 12; j++){
    f16x8 h8 = ((const f16x8*)rowL)[j * 64 + lane];
#pragma unroll
    for (int e = 0; e < 8; e++){
      float v = (float)h8[e];
      float dcd = v - BPd;
      float f = ((v < BPd) ? C_COEF : 2.f * C_COEF) * dcd;
      float sp = softplus_f(-f);
      bool use = (v != BPd);
      anA += use ? sp : 0.f;
      cnA += use ? 1.f : 0.f;
    }
  }
  float anS = 0.f, cnS = 0.f, ap = 0.f, cp = 0.f;
  for (int t = lane; t < ns; t += 64){
    float v = simget(simv, rowp, mlist, t);
    float dcd = v - BPd;
    float f = ((v < BPd) ? C_COEF : 2.f * C_COEF) * dcd;
    if (v != BPd){ anS += softplus_f(-f); cnS += 1.f; }   // bitwise-identical terms
    if (v != BP){
      float dc = v - BP;
      float f2 = ((v > BP) ? C_COEF : 2.f * C_COEF) * dc;
      ap += softplus_f(f2); cp += 1.f;
    }
  }
  const float an = waveAllRedF(anA) - waveAllRedF(anS);
  const float cn = waveAllRedF(cnA) - waveAllRedF(cnS);
  const float apT = waveAllRedF(ap);
  const float cpT = waveAllRedF(cp);
  if (lane == 0){
    atomicAdd(&accf[1], apT / fmaxf(cpT, 1.f));
    atomicAdd(&accf[2], an / fmaxf(cn, 1.f));
    atomicAdd(&acci[3], 1);
  }
}

__global__ void k_final(const float* __restrict__ accf, const int* __restrict__ acci,
                        float* __restrict__ out){
  if (threadIdx.x == 0 && blockIdx.x == 0){
    int c = acci[3];
    float posL = 0.f, navL = 0.f;
    if (c > 0){ posL = accf[1] / (float)c; navL = accf[2] / (float)c; }
    out[0] = posL + navL + 0.1f * (accf[0] / (float)(NROW * KDIM));
  }
}

extern "C" void kernel_launch(void* const* d_in, const int* in_sizes, int n_in,
                              void* d_out, int out_size, void* d_ws, size_t ws_size,
                              hipStream_t stream){
  const float* u = (const float*)d_in[0];
  const int* y = (const int*)d_in[1];
  char* ws = (char*)d_ws;
  float* accf = (float*)ws;                        // [0]=qSum [1]=posSum [2]=negSum
  int* acci = (int*)ws;                            // [3]=validCount
  int* cnt = (int*)(ws + 64);                      // 256 ints
  unsigned char* lab = (unsigned char*)(ws + 4096);        // 6144 B
  int* simIdx = (int*)(ws + 12288);                // 200*512 ints = 409600 B
  _Float16* uhswz = (_Float16*)(ws + 425984);      // 1572864 B
  const size_t ibufOff = 425984 + (size_t)NROW * KDIM * 2; // 1998848, 16B aligned
  _Float16* ibuf = (_Float16*)(ws + ibufOff);

  hipMemsetAsync(d_ws, 0, 4096, stream);           // accumulators + class counts
  k_label<<<NROW, 256, 0, stream>>>(y, lab, cnt, simIdx);
  k_tanh<<<(NROW * 16) / 256, 256, 0, stream>>>(u, uhswz, accf);

  size_t avail = (ws_size > ibufOff) ? ws_size - ibufOff : 0;
  long maxRows = (long)(avail / ((size_t)NROW * 2));
  maxRows = (maxRows / 128) * 128;
  if (maxRows > NROW) maxRows = NROW;
  if (maxRows < 128) maxRows = 128;

  for (int r0 = 0; r0 < NROW; r0 += (int)maxRows){
    int rows = NROW - r0;
    if (rows > maxRows) rows = (int)maxRows;
    k_mm<<<dim3(48, rows / 128), 256, 0, stream>>>(uhswz, ibuf, r0);
    k_stats<<<rows / 4, 256, 0, stream>>>(ibuf, lab, cnt, simIdx, accf, acci, r0);
  }
  k_final<<<1, 64, 0, stream>>>(accf, acci, (float*)d_out);
}